// Round 8
// baseline (169.096 us; speedup 1.0000x reference)
//
#include <hip/hip_runtime.h>
#include <stdint.h>

#define V3 110592        // 48*48*48
#define PLANE 2304       // 48*48
#define NO 64

typedef unsigned short ushort_t;
typedef __attribute__((ext_vector_type(8))) short short8v;
typedef __attribute__((ext_vector_type(4))) float float4v;

__device__ __forceinline__ uint32_t f2bf1(float f) {
  uint32_t u = __float_as_uint(f);
  u += 0x7FFFu + ((u >> 16) & 1u);   // RNE
  return u >> 16;
}
__device__ __forceinline__ uint32_t pack2(float a, float b) {
  return f2bf1(a) | (f2bf1(b) << 16);
}

// prep folded into bq: blocks (x, y<5, z==0) cover idx = (y*48+x)*256+tid
// = exactly [0, 61440). Afr[g][m][8] bf16, kk = dzi*192 + i*6 + qi, g=kk/8.
__device__ __forceinline__ void prep_body(const float* __restrict__ w,
                                          ushort_t* __restrict__ Afr, int idx) {
  int r = idx & 7, m = (idx >> 3) & 63, g = idx >> 9;
  int kk = g * 8 + r;
  int dzi = kk / 192, k2 = kk % 192;
  int i = k2 / 6, qi = k2 % 6;
  const int Q[6] = {0, 1, 2, 4, 5, 8};
  const int pidx[13] = {0, 1, 2, 3, 4, 5, 6, 0, 7, 8, 0, 0, 9};  // r2 -> shell
  int dz = dzi - 2;
  int p = pidx[Q[qi] + dz * dz];
  Afr[idx] = (ushort_t)f2bf1(0.28209479177387814f * w[(m * 32 + i) * 10 + p]);
}

// ---------- pass 1: per-plane 2D class sums; NO LDS, NO barriers ----------
// R4 (verified): two-phase (all 40 loads first, then shfl/reduce/store) took
// bq to ~its memory floor (~16-18 us per batch). Kept as-is.
__global__ __launch_bounds__(256, 4) void bq_kernel(const float* __restrict__ x,
                                                    ushort_t* __restrict__ Bq,
                                                    const float* __restrict__ w,
                                                    ushort_t* __restrict__ Afr) {
  const int tid = threadIdx.x;
  if (blockIdx.z == 0 && blockIdx.y < 5)
    prep_body(w, Afr, (blockIdx.y * 48 + blockIdx.x) * 256 + tid);

  const int lane = tid & 63;
  const int strip = tid >> 6;                    // 0..3 within block
  const int d = blockIdx.x;                      // 0..47
  const int ig = blockIdx.y & 7;                 // 0..7 channel group
  const int half = blockIdx.y >> 3;              // 0..1 strip half
  const float* xb = x + (size_t)blockIdx.z * 32 * V3;
  ushort_t* Bqb = Bq + (size_t)blockIdx.z * ((size_t)1152 * PLANE * 8);

  const int h0 = (half * 4 + strip) * 6;         // 6-row strip base
  const int gw = lane - 2;
  const bool okw = (gw >= 0 && gw < 48);
  const int sl1 = lane > 0 ? lane - 1 : 0;
  const int sl2 = lane > 1 ? lane - 2 : 0;
  const int sr1 = lane < 63 ? lane + 1 : 63;
  const int sr2 = lane < 62 ? lane + 2 : 63;
  const bool okst = (lane >= 2 && lane <= 49);

  const float* px[4];
#pragma unroll
  for (int ii = 0; ii < 4; ++ii)
    px[ii] = xb + ((size_t)(ig * 4 + ii) * 48 + d) * PLANE + gw;

  // phase 1: all loads in flight (independent addresses, one vmcnt chain)
  float v[10][4];
#pragma unroll
  for (int r = 0; r < 10; ++r) {
    const int gh = h0 - 2 + r;
    const bool okv = okw && (gh >= 0) && (gh < 48);
#pragma unroll
    for (int ii = 0; ii < 4; ++ii)
      v[r][ii] = okv ? px[ii][gh * 48] : 0.f;
  }

  // phase 2: shfl class-sums with rolling windows; a0 terms read v[] directly
  float s1[4][5], s4[4][5];
#pragma unroll
  for (int r = 0; r < 10; ++r) {
    const int slot = r % 5;
#pragma unroll
    for (int ii = 0; ii < 4; ++ii) {
      float val = v[r][ii];
      float vl1 = __shfl(val, sl1);
      float vr1 = __shfl(val, sr1);
      float vl2 = __shfl(val, sl2);
      float vr2 = __shfl(val, sr2);
      s1[ii][slot] = vl1 + vr1;                  // dx^2 = 1
      s4[ii][slot] = vl2 + vr2;                  // dx^2 = 4
    }
    if (r >= 4) {
      const int j0 = (r - 4) % 5, j1 = (r - 3) % 5, j2 = (r - 2) % 5,
                j3 = (r - 1) % 5, j4 = r % 5;    // j = dy offset 0..4
      uint32_t dw[12];
#pragma unroll
      for (int ii = 0; ii < 4; ++ii) {
        float B0 = v[r - 2][ii];
        float B1 = s1[ii][j2] + v[r - 3][ii] + v[r - 1][ii];
        float B2 = s1[ii][j1] + s1[ii][j3];
        float B3 = s4[ii][j2] + v[r - 4][ii] + v[r][ii];
        float B4 = s4[ii][j1] + s4[ii][j3] + s1[ii][j0] + s1[ii][j4];
        float B5 = s4[ii][j0] + s4[ii][j4];
        dw[ii * 3 + 0] = pack2(B0, B1);
        dw[ii * 3 + 1] = pack2(B2, B3);
        dw[ii * 3 + 2] = pack2(B4, B5);
      }
      if (okst) {
        const int n = (h0 + r - 4) * 48 + gw;
        const size_t gb = (size_t)(d * 24 + ig * 3);
        uint4 c0 = {dw[0], dw[1], dw[2], dw[3]};
        uint4 c1 = {dw[4], dw[5], dw[6], dw[7]};
        uint4 c2 = {dw[8], dw[9], dw[10], dw[11]};
        *(uint4*)(Bqb + ((gb + 0) * PLANE + n) * 8) = c0;
        *(uint4*)(Bqb + ((gb + 1) * PLANE + n) * 8) = c1;
        *(uint4*)(Bqb + ((gb + 2) * PLANE + n) * 8) = c2;
      }
    }
  }
}

// ---------- pass 2: plane-major GEMM with per-wave LDS B-FIFO ----------
// out[m][d,n] = sum_kk Afr[kk][m] * Bq[(d-2)*24 + kk/8][n][kk%8] + bias[m]
// XCD partition (verified R1: FETCH 207.8 -> 83.4 MB): b&7 -> XCD.
// R8: R3-R7 lesson: ANY latency-hiding scheme held in named registers gets
// collapsed by the pre-RA scheduler (VGPR 56/60/64/72/124 across attempts;
// never the designed ~190). The one mechanism it cannot collapse is the
// global_load_lds queue: B-frags are staged 2 trips ahead into a PRIVATE
// per-wave 3-slot LDS FIFO (memory, invisible to regalloc), drained by an
// explicit counted `s_waitcnt vmcnt(2)` (the compiler can't see the
// gload_lds->ds_read dep, so it can't "optimize" the pipeline away; it still
// inserts its own waits for the A register loads). NO barriers: slots are
// wave-private, so no inter-wave coupling, no drain stall, no race surface.
// FIFO induction (A issued before stage in each trip):
//   outstanding before wait @trip t = B(t+1):2 + A(t):4 + B(t+2):2 = 8
//   vmcnt(2) completes B(t+1)+A(t), leaves B(t+2) in flight. B(t) was
//   completed by trip t-1's wait. Tail: T-2 -> vmcnt(2), T-1 -> vmcnt(0).
// VGPR ~76 (acc32+A16+Bf8+addr), LDS 24KB -> ~6 blocks/CU, ~24 waves/CU
// (vs R7's 4). L1 cap: 6KB/trip / 38.8 CU-cy = 158 B/cy vs 128 -> ~80%
// MfmaUtil ceiling, plenty above the current 17%.
__global__ __launch_bounds__(256, 6) void gemm_kernel(const ushort_t* __restrict__ Bq,
                                                      const ushort_t* __restrict__ Afr,
                                                      const float* __restrict__ bias,
                                                      float* __restrict__ out) {
  const int tid = threadIdx.x;
  const int lane = tid & 63, wi = tid >> 6;
  const int quad = lane >> 4, m15 = lane & 15;
  const int b = blockIdx.x;                      // 0..863 flat
  const int p = b & 7;                           // XCD partition
  const int s = b >> 3;                          // 0..107 within partition
  const int dl = s / 9;                          // 0..11
  const int nbl = s - dl * 9;                    // 0..8
  const int d = (p >> 1) * 12 + dl;              // output plane
  const int n0 = ((p & 1) * 9 + nbl) * 128 + wi * 32;
  const ushort_t* Bqb = Bq + (size_t)blockIdx.z * ((size_t)1152 * PLANE * 8);
  float* outb = out + (size_t)blockIdx.z * (size_t)NO * V3;

  const int lo = (d < 2) ? (2 - d) : 0;          // dzi range [lo,hi]
  const int hi = (d > 45) ? (49 - d) : 4;
  const int kslo = 6 * lo;
  const int T = 6 * (hi - lo + 1);               // trips: 18/24/30 (mult of 6)

  const ushort_t* ap = Afr + ((size_t)(kslo * 4 + quad) * 64 + m15) * 8;
  const ushort_t* bp = Bqb + ((size_t)((d - 2) * 24 + kslo * 4 + quad) * PLANE + n0 + m15) * 8;
  const int astep = 4 * 64 * 8;                  // shorts per trip
  const int bstep = 4 * PLANE * 8;

  __shared__ ushort_t sB[4][3][2][512];          // [wave][slot][nt][1KB] = 24KB

  float4v acc[4][2];
#pragma unroll
  for (int mt = 0; mt < 4; ++mt)
#pragma unroll
    for (int nt = 0; nt < 2; ++nt) acc[mt][nt] = (float4v){0.f, 0.f, 0.f, 0.f};

  short8v A[4], Bf[2];

  // stage: 2 x global_load_lds width-16. LDS dest = wave-uniform slot base
  // (HW adds lane*16); global src = this lane's exact B-frag address, so the
  // linear LDS readback at lane*16 returns exactly what this lane needs.
#define STAGE(SL)                                                              \
  {                                                                            \
    _Pragma("unroll") for (int nt = 0; nt < 2; ++nt)                           \
        __builtin_amdgcn_global_load_lds(                                      \
            (const __attribute__((address_space(1))) void*)(bp + nt * 128),    \
            (__attribute__((address_space(3))) void*)&sB[wi][SL][nt][0],       \
            16, 0, 0);                                                         \
    bp += bstep;                                                               \
  }
#define TRIP(SL, DO_STAGE, SSL, VMC)                                           \
  {                                                                            \
    _Pragma("unroll") for (int mt = 0; mt < 4; ++mt)                           \
        A[mt] = *(const short8v*)(ap + mt * 128);                              \
    ap += astep;                                                               \
    if (DO_STAGE) STAGE(SSL);                                                  \
    asm volatile("s_waitcnt vmcnt(" VMC ")" ::: "memory");                     \
    _Pragma("unroll") for (int nt = 0; nt < 2; ++nt)                           \
        Bf[nt] = *(const short8v*)&sB[wi][SL][nt][lane * 8];                   \
    __builtin_amdgcn_s_setprio(1);                                             \
    _Pragma("unroll") for (int mt = 0; mt < 4; ++mt)                           \
        _Pragma("unroll") for (int nt = 0; nt < 2; ++nt)                       \
            acc[mt][nt] = __builtin_amdgcn_mfma_f32_16x16x32_bf16(             \
                A[mt], Bf[nt], acc[mt][nt], 0, 0, 0);                          \
    __builtin_amdgcn_s_setprio(0);                                             \
  }

  STAGE(0);                                      // trip 0
  STAGE(1);                                      // trip 1
  for (int k = 0; k + 3 < T; k += 3) {           // trips 0 .. T-4
    TRIP(0, true, 2, "2");
    TRIP(1, true, 0, "2");
    TRIP(2, true, 1, "2");
  }
  TRIP(0, true, 2, "2");                         // t = T-3, stages T-1
  TRIP(1, false, 0, "2");                        // t = T-2
  TRIP(2, false, 0, "0");                        // t = T-1, full drain
#undef STAGE
#undef TRIP

  // C/D: col(n) = lane&15, row(m) = quad*4 + reg
  const int vb = d * PLANE + n0 + m15;
#pragma unroll
  for (int mt = 0; mt < 4; ++mt) {
#pragma unroll
    for (int r = 0; r < 4; ++r) {
      int m = mt * 16 + quad * 4 + r;
      float bv = bias[m];
      float* op = outb + (size_t)m * V3 + vb;
#pragma unroll
      for (int nt = 0; nt < 2; ++nt)
        op[nt * 16] = acc[mt][nt][r] + bv;
    }
  }
}

extern "C" void kernel_launch(void* const* d_in, const int* in_sizes, int n_in,
                              void* d_out, int out_size, void* d_ws, size_t ws_size,
                              hipStream_t stream) {
  const float* x    = (const float*)d_in[0];   // [2,32,1,48,48,48]
  const float* w    = (const float*)d_in[1];   // [64,32,1,1,1,10]
  const float* bias = (const float*)d_in[2];   // [64]
  float* out = (float*)d_out;                  // [2,64,1,48,48,48]

  ushort_t* Afr = (ushort_t*)d_ws;                         // 122880 B
  ushort_t* Bq  = (ushort_t*)((char*)d_ws + 131072);
  const size_t SB = (size_t)1152 * PLANE * 8 * 2;          // 42.5 MB per batch
  const bool both = (ws_size >= 131072 + 2 * SB);

  if (both) {
    bq_kernel<<<dim3(48, 16, 2), 256, 0, stream>>>(x, Bq, w, Afr);
    gemm_kernel<<<dim3(864, 1, 2), 256, 0, stream>>>(Bq, Afr, bias, out);
  } else {
    for (int b = 0; b < 2; ++b) {
      bq_kernel<<<dim3(48, 16, 1), 256, 0, stream>>>(x + (size_t)b * 32 * V3, Bq, w, Afr);
      gemm_kernel<<<dim3(864, 1, 1), 256, 0, stream>>>(Bq, Afr, bias,
                                                       out + (size_t)b * NO * V3);
    }
  }
}

// Round 10
// 149.045 us; speedup vs baseline: 1.1345x; 1.1345x over previous
//
#include <hip/hip_runtime.h>
#include <stdint.h>

#define V3 110592        // 48*48*48
#define PLANE 2304       // 48*48
#define NO 64

typedef unsigned short ushort_t;
typedef __attribute__((ext_vector_type(8))) short short8v;
typedef __attribute__((ext_vector_type(4))) float float4v;

__device__ __forceinline__ uint32_t f2bf1(float f) {
  uint32_t u = __float_as_uint(f);
  u += 0x7FFFu + ((u >> 16) & 1u);   // RNE
  return u >> 16;
}
__device__ __forceinline__ uint32_t pack2(float a, float b) {
  return f2bf1(a) | (f2bf1(b) << 16);
}

// Afr[g][m][8] bf16, kk = dzi*192 + i*6 + qi, g=kk/8.
__device__ __forceinline__ void prep_body(const float* __restrict__ w,
                                          ushort_t* __restrict__ Afr, int idx) {
  int r = idx & 7, m = (idx >> 3) & 63, g = idx >> 9;
  int kk = g * 8 + r;
  int dzi = kk / 192, k2 = kk % 192;
  int i = k2 / 6, qi = k2 % 6;
  const int Q[6] = {0, 1, 2, 4, 5, 8};
  const int pidx[13] = {0, 1, 2, 3, 4, 5, 6, 0, 7, 8, 0, 0, 9};  // r2 -> shell
  int dz = dzi - 2;
  int p = pidx[Q[qi] + dz * dz];
  Afr[idx] = (ushort_t)f2bf1(0.28209479177387814f * w[(m * 32 + i) * 10 + p]);
}

// ---------- pass 1: per-plane 2D class sums (R4-verified body) ----------
// R10: writer->reader XCD alignment. bq's row-half (rows 0-23 vs 24-47)
// equals gemm's n-half (cols 0-1151 vs 1152-2303). Flat blockIdx decode puts
// the (d, half) producer on XCD q = (d/12)*2 + half — the SAME XCD whose
// gemm partition reads that half-plane, so Bq lines written to this XCD's L2
// are still resident (and local) when gemm runs. R5 evidence: 30 MB of Bq
// already survived dispatch-to-dispatch even MISaligned (FETCH 55 < 85 MB
// unique); alignment should push most B-reads to local-XCD L2 hits.
// decode: q=b&7 -> dg=q>>1, half=q&1; s=b>>3 -> dl=s%12, ig=(s/12)%8,
// z=zbase+s/96. Bijection over (d, ig, half, z).
__global__ __launch_bounds__(256, 4) void bq_kernel(const float* __restrict__ x,
                                                    ushort_t* __restrict__ Bq,
                                                    const float* __restrict__ w,
                                                    ushort_t* __restrict__ Afr,
                                                    int zbase) {
  const int tid = threadIdx.x;
  const int b = blockIdx.x;
  if (zbase == 0 && b < 240) prep_body(w, Afr, b * 256 + tid);

  const int q = b & 7;
  const int dg = q >> 1, half = q & 1;
  const int s = b >> 3;
  const int dl = s % 12;
  const int ig = (s / 12) & 7;
  const int z = zbase + s / 96;
  const int d = dg * 12 + dl;

  const int lane = tid & 63;
  const int strip = tid >> 6;                    // 0..3
  const float* xb = x + (size_t)z * 32 * V3;
  ushort_t* Bqb = Bq + (size_t)z * ((size_t)1152 * PLANE * 8);

  const int h0 = (half * 4 + strip) * 6;         // 6-row strip base
  const int gw = lane - 2;
  const bool okw = (gw >= 0 && gw < 48);
  const int sl1 = lane > 0 ? lane - 1 : 0;
  const int sl2 = lane > 1 ? lane - 2 : 0;
  const int sr1 = lane < 63 ? lane + 1 : 63;
  const int sr2 = lane < 62 ? lane + 2 : 63;
  const bool okst = (lane >= 2 && lane <= 49);

  const float* px[4];
#pragma unroll
  for (int ii = 0; ii < 4; ++ii)
    px[ii] = xb + ((size_t)(ig * 4 + ii) * 48 + d) * PLANE + gw;

  // phase 1: all loads in flight
  float v[10][4];
#pragma unroll
  for (int r = 0; r < 10; ++r) {
    const int gh = h0 - 2 + r;
    const bool okv = okw && (gh >= 0) && (gh < 48);
#pragma unroll
    for (int ii = 0; ii < 4; ++ii)
      v[r][ii] = okv ? px[ii][gh * 48] : 0.f;
  }

  // phase 2: shfl class-sums
  float s1[4][5], s4[4][5];
#pragma unroll
  for (int r = 0; r < 10; ++r) {
    const int slot = r % 5;
#pragma unroll
    for (int ii = 0; ii < 4; ++ii) {
      float val = v[r][ii];
      float vl1 = __shfl(val, sl1);
      float vr1 = __shfl(val, sr1);
      float vl2 = __shfl(val, sl2);
      float vr2 = __shfl(val, sr2);
      s1[ii][slot] = vl1 + vr1;                  // dx^2 = 1
      s4[ii][slot] = vl2 + vr2;                  // dx^2 = 4
    }
    if (r >= 4) {
      const int j0 = (r - 4) % 5, j1 = (r - 3) % 5, j2 = (r - 2) % 5,
                j3 = (r - 1) % 5, j4 = r % 5;
      uint32_t dw[12];
#pragma unroll
      for (int ii = 0; ii < 4; ++ii) {
        float B0 = v[r - 2][ii];
        float B1 = s1[ii][j2] + v[r - 3][ii] + v[r - 1][ii];
        float B2 = s1[ii][j1] + s1[ii][j3];
        float B3 = s4[ii][j2] + v[r - 4][ii] + v[r][ii];
        float B4 = s4[ii][j1] + s4[ii][j3] + s1[ii][j0] + s1[ii][j4];
        float B5 = s4[ii][j0] + s4[ii][j4];
        dw[ii * 3 + 0] = pack2(B0, B1);
        dw[ii * 3 + 1] = pack2(B2, B3);
        dw[ii * 3 + 2] = pack2(B4, B5);
      }
      if (okst) {
        const int n = (h0 + r - 4) * 48 + gw;
        const size_t gb = (size_t)(d * 24 + ig * 3);
        uint4 c0 = {dw[0], dw[1], dw[2], dw[3]};
        uint4 c1 = {dw[4], dw[5], dw[6], dw[7]};
        uint4 c2 = {dw[8], dw[9], dw[10], dw[11]};
        *(uint4*)(Bqb + ((gb + 0) * PLANE + n) * 8) = c0;
        *(uint4*)(Bqb + ((gb + 1) * PLANE + n) * 8) = c1;
        *(uint4*)(Bqb + ((gb + 2) * PLANE + n) * 8) = c2;
      }
    }
  }
}

// ---------- pass 2: plane-major GEMM (R5-verified body) ----------
// out[m][d,n] = sum_kk Afr[kk][m] * Bq[(d-2)*24 + kk/8][n][kk%8] + bias[m]
// XCD partition p=b&7 owns (d_group = p>>1, n_half = p&1) — now matched by
// the bq writer mapping above. R10 adds __builtin_nontemporal_store for out:
// 110 MB of write-once output was write-allocating in L2 and evicting the
// Bq lines gemm is reusing; `nt` stops the pollution.
__global__ __launch_bounds__(256, 4) void gemm_kernel(const ushort_t* __restrict__ Bq,
                                                      const ushort_t* __restrict__ Afr,
                                                      const float* __restrict__ bias,
                                                      float* __restrict__ out) {
  const int tid = threadIdx.x;
  const int lane = tid & 63, wi = tid >> 6;
  const int quad = lane >> 4, m15 = lane & 15;
  const int b = blockIdx.x;                      // 0..863 flat
  const int p = b & 7;                           // XCD partition
  const int s = b >> 3;                          // 0..107
  const int dl = s / 9;                          // 0..11
  const int nbl = s - dl * 9;                    // 0..8
  const int d = (p >> 1) * 12 + dl;              // output plane
  const int n0 = ((p & 1) * 9 + nbl) * 128 + wi * 32;
  const ushort_t* Bqb = Bq + (size_t)blockIdx.z * ((size_t)1152 * PLANE * 8);
  float* outb = out + (size_t)blockIdx.z * (size_t)NO * V3;

  const int lo = (d < 2) ? (2 - d) : 0;
  const int hi = (d > 45) ? (49 - d) : 4;
  const int kslo = 6 * lo;
  const int T = 6 * (hi - lo + 1);               // 18/24/30 (mult of 6)

  const ushort_t* ap = Afr + ((size_t)(kslo * 4 + quad) * 64 + m15) * 8;
  const ushort_t* bp = Bqb + ((size_t)((d - 2) * 24 + kslo * 4 + quad) * PLANE + n0 + m15) * 8;
  const int astep = 4 * 64 * 8;
  const int bstep = 4 * PLANE * 8;

  float4v acc[4][2];
#pragma unroll
  for (int mt = 0; mt < 4; ++mt)
#pragma unroll
    for (int nt = 0; nt < 2; ++nt) acc[mt][nt] = (float4v){0.f, 0.f, 0.f, 0.f};

  short8v A0[4], B0[2], A1[4], B1[2], A2[4], B2[2];

#define SBAR __builtin_amdgcn_sched_barrier(0)
#define LOADSET(Ax, Bx)                                                        \
  {                                                                            \
    _Pragma("unroll") for (int nt = 0; nt < 2; ++nt)                           \
        Bx[nt] = *(const short8v*)(bp + nt * 128);                             \
    _Pragma("unroll") for (int mt = 0; mt < 4; ++mt)                           \
        Ax[mt] = *(const short8v*)(ap + mt * 128);                             \
    ap += astep; bp += bstep;                                                  \
  }
#define MFMASET(Ax, Bx)                                                        \
  {                                                                            \
    __builtin_amdgcn_s_setprio(1);                                             \
    _Pragma("unroll") for (int mt = 0; mt < 4; ++mt)                           \
        _Pragma("unroll") for (int nt = 0; nt < 2; ++nt)                       \
            acc[mt][nt] = __builtin_amdgcn_mfma_f32_16x16x32_bf16(             \
                Ax[mt], Bx[nt], acc[mt][nt], 0, 0, 0);                         \
    __builtin_amdgcn_s_setprio(0);                                             \
  }

  LOADSET(A0, B0);
  LOADSET(A1, B1);
  SBAR;
  for (int k = 0; k < T - 3; k += 3) {
    LOADSET(A2, B2); SBAR;
    MFMASET(A0, B0); SBAR;
    LOADSET(A0, B0); SBAR;
    MFMASET(A1, B1); SBAR;
    LOADSET(A1, B1); SBAR;
    MFMASET(A2, B2); SBAR;
  }
  LOADSET(A2, B2); SBAR;
  MFMASET(A0, B0);
  MFMASET(A1, B1);
  MFMASET(A2, B2);
#undef LOADSET
#undef MFMASET
#undef SBAR

  // C/D: col(n) = lane&15, row(m) = quad*4 + reg; nontemporal out stores
  const int vb = d * PLANE + n0 + m15;
#pragma unroll
  for (int mt = 0; mt < 4; ++mt) {
#pragma unroll
    for (int r = 0; r < 4; ++r) {
      int m = mt * 16 + quad * 4 + r;
      float bv = bias[m];
      float* op = outb + (size_t)m * V3 + vb;
#pragma unroll
      for (int nt = 0; nt < 2; ++nt)
        __builtin_nontemporal_store(acc[mt][nt][r] + bv, op + nt * 16);
    }
  }
}

extern "C" void kernel_launch(void* const* d_in, const int* in_sizes, int n_in,
                              void* d_out, int out_size, void* d_ws, size_t ws_size,
                              hipStream_t stream) {
  const float* x    = (const float*)d_in[0];   // [2,32,1,48,48,48]
  const float* w    = (const float*)d_in[1];   // [64,32,1,1,1,10]
  const float* bias = (const float*)d_in[2];   // [64]
  float* out = (float*)d_out;                  // [2,64,1,48,48,48]

  ushort_t* Afr = (ushort_t*)d_ws;                         // 122880 B
  ushort_t* Bq  = (ushort_t*)((char*)d_ws + 131072);
  const size_t SB = (size_t)1152 * PLANE * 8 * 2;          // 42.5 MB per batch
  const bool both = (ws_size >= 131072 + 2 * SB);

  if (both) {
    bq_kernel<<<dim3(1536), 256, 0, stream>>>(x, Bq, w, Afr, 0);
    gemm_kernel<<<dim3(864, 1, 2), 256, 0, stream>>>(Bq, Afr, bias, out);
  } else {
    for (int b = 0; b < 2; ++b) {
      bq_kernel<<<dim3(768), 256, 0, stream>>>(x + (size_t)b * 32 * V3, Bq, w, Afr, 0);
      gemm_kernel<<<dim3(864, 1, 1), 256, 0, stream>>>(Bq, Afr, bias,
                                                       out + (size_t)b * NO * V3);
    }
  }
}

// Round 11
// 148.926 us; speedup vs baseline: 1.1354x; 1.0008x over previous
//
#include <hip/hip_runtime.h>
#include <stdint.h>

#define V3 110592        // 48*48*48
#define PLANE 2304       // 48*48
#define NO 64

typedef unsigned short ushort_t;
typedef __attribute__((ext_vector_type(8))) short short8v;
typedef __attribute__((ext_vector_type(4))) float float4v;

__device__ __forceinline__ uint32_t f2bf1(float f) {
  uint32_t u = __float_as_uint(f);
  u += 0x7FFFu + ((u >> 16) & 1u);   // RNE
  return u >> 16;
}
__device__ __forceinline__ uint32_t pack2(float a, float b) {
  return f2bf1(a) | (f2bf1(b) << 16);
}

// Afr[g][m][8] bf16, kk = dzi*192 + i*6 + qi, g=kk/8.
__device__ __forceinline__ void prep_body(const float* __restrict__ w,
                                          ushort_t* __restrict__ Afr, int idx) {
  int r = idx & 7, m = (idx >> 3) & 63, g = idx >> 9;
  int kk = g * 8 + r;
  int dzi = kk / 192, k2 = kk % 192;
  int i = k2 / 6, qi = k2 % 6;
  const int Q[6] = {0, 1, 2, 4, 5, 8};
  const int pidx[13] = {0, 1, 2, 3, 4, 5, 6, 0, 7, 8, 0, 0, 9};  // r2 -> shell
  int dz = dzi - 2;
  int p = pidx[Q[qi] + dz * dz];
  Afr[idx] = (ushort_t)f2bf1(0.28209479177387814f * w[(m * 32 + i) * 10 + p]);
}

// ---------- pass 1: per-plane 2D class sums (R4-verified body) ----------
// R10 (kept): writer->reader XCD alignment — (d, half) producer runs on the
// XCD whose gemm partition reads that half-plane.
__global__ __launch_bounds__(256, 4) void bq_kernel(const float* __restrict__ x,
                                                    ushort_t* __restrict__ Bq,
                                                    const float* __restrict__ w,
                                                    ushort_t* __restrict__ Afr,
                                                    int zbase) {
  const int tid = threadIdx.x;
  const int b = blockIdx.x;
  if (zbase == 0 && b < 240) prep_body(w, Afr, b * 256 + tid);

  const int q = b & 7;
  const int dg = q >> 1, half = q & 1;
  const int s = b >> 3;
  const int dl = s % 12;
  const int ig = (s / 12) & 7;
  const int z = zbase + s / 96;
  const int d = dg * 12 + dl;

  const int lane = tid & 63;
  const int strip = tid >> 6;                    // 0..3
  const float* xb = x + (size_t)z * 32 * V3;
  ushort_t* Bqb = Bq + (size_t)z * ((size_t)1152 * PLANE * 8);

  const int h0 = (half * 4 + strip) * 6;         // 6-row strip base
  const int gw = lane - 2;
  const bool okw = (gw >= 0 && gw < 48);
  const int sl1 = lane > 0 ? lane - 1 : 0;
  const int sl2 = lane > 1 ? lane - 2 : 0;
  const int sr1 = lane < 63 ? lane + 1 : 63;
  const int sr2 = lane < 62 ? lane + 2 : 63;
  const bool okst = (lane >= 2 && lane <= 49);

  const float* px[4];
#pragma unroll
  for (int ii = 0; ii < 4; ++ii)
    px[ii] = xb + ((size_t)(ig * 4 + ii) * 48 + d) * PLANE + gw;

  // phase 1: all loads in flight
  float v[10][4];
#pragma unroll
  for (int r = 0; r < 10; ++r) {
    const int gh = h0 - 2 + r;
    const bool okv = okw && (gh >= 0) && (gh < 48);
#pragma unroll
    for (int ii = 0; ii < 4; ++ii)
      v[r][ii] = okv ? px[ii][gh * 48] : 0.f;
  }

  // phase 2: shfl class-sums
  float s1[4][5], s4[4][5];
#pragma unroll
  for (int r = 0; r < 10; ++r) {
    const int slot = r % 5;
#pragma unroll
    for (int ii = 0; ii < 4; ++ii) {
      float val = v[r][ii];
      float vl1 = __shfl(val, sl1);
      float vr1 = __shfl(val, sr1);
      float vl2 = __shfl(val, sl2);
      float vr2 = __shfl(val, sr2);
      s1[ii][slot] = vl1 + vr1;                  // dx^2 = 1
      s4[ii][slot] = vl2 + vr2;                  // dx^2 = 4
    }
    if (r >= 4) {
      const int j0 = (r - 4) % 5, j1 = (r - 3) % 5, j2 = (r - 2) % 5,
                j3 = (r - 1) % 5, j4 = r % 5;
      uint32_t dw[12];
#pragma unroll
      for (int ii = 0; ii < 4; ++ii) {
        float B0 = v[r - 2][ii];
        float B1 = s1[ii][j2] + v[r - 3][ii] + v[r - 1][ii];
        float B2 = s1[ii][j1] + s1[ii][j3];
        float B3 = s4[ii][j2] + v[r - 4][ii] + v[r][ii];
        float B4 = s4[ii][j1] + s4[ii][j3] + s1[ii][j0] + s1[ii][j4];
        float B5 = s4[ii][j0] + s4[ii][j4];
        dw[ii * 3 + 0] = pack2(B0, B1);
        dw[ii * 3 + 1] = pack2(B2, B3);
        dw[ii * 3 + 2] = pack2(B4, B5);
      }
      if (okst) {
        const int n = (h0 + r - 4) * 48 + gw;
        const size_t gb = (size_t)(d * 24 + ig * 3);
        uint4 c0 = {dw[0], dw[1], dw[2], dw[3]};
        uint4 c1 = {dw[4], dw[5], dw[6], dw[7]};
        uint4 c2 = {dw[8], dw[9], dw[10], dw[11]};
        *(uint4*)(Bqb + ((gb + 0) * PLANE + n) * 8) = c0;
        *(uint4*)(Bqb + ((gb + 1) * PLANE + n) * 8) = c1;
        *(uint4*)(Bqb + ((gb + 2) * PLANE + n) * 8) = c2;
      }
    }
  }
}

// ---------- pass 2: plane-major GEMM, inline-asm depth-3 pipeline ----------
// out[m][d,n] = sum_kk Afr[kk][m] * Bq[(d-2)*24 + kk/8][n][kk%8] + bias[m]
// R11: R3-R10 showed hipcc's pre-RA pressure heuristic dismantles EVERY
// source-level pipeline (VGPR_Count 56-72 vs the ~116 designed; MfmaUtil
// pinned ~19%). Escape hatch: inline-asm global_load_dwordx4 with "=v"
// outputs — volatile asm defs the allocator cannot sink/rematerialize/
// collapse — plus explicit counted s_waitcnt vmcnt(12) (AITER pattern,
// never 0 in steady state) and sched_barrier(0) after each wait (rule #18:
// stops MFMA hoisting above the wait). Depth-3 rotation:
//   prologue: ISSUE(L0), ISSUE(L1)            -> 12 outstanding
//   phase k : ISSUE(L(k+2)) -> 18; vmcnt(12) completes L(k); MFMA(k)
//   tail    : vmcnt(12)/(6)/(0) drain for the last three trips.
// Registers: 3 bufs x 24 (asm-forced live) + 32 acc + addr ~ 115 < 128 cap.
__global__ __launch_bounds__(256, 4) void gemm_kernel(const ushort_t* __restrict__ Bq,
                                                      const ushort_t* __restrict__ Afr,
                                                      const float* __restrict__ bias,
                                                      float* __restrict__ out) {
  const int tid = threadIdx.x;
  const int lane = tid & 63, wi = tid >> 6;
  const int quad = lane >> 4, m15 = lane & 15;
  const int b = blockIdx.x;                      // 0..863 flat
  const int p = b & 7;                           // XCD partition
  const int s = b >> 3;                          // 0..107
  const int dl = s / 9;                          // 0..11
  const int nbl = s - dl * 9;                    // 0..8
  const int d = (p >> 1) * 12 + dl;              // output plane
  const int n0 = ((p & 1) * 9 + nbl) * 128 + wi * 32;
  const ushort_t* Bqb = Bq + (size_t)blockIdx.z * ((size_t)1152 * PLANE * 8);
  float* outb = out + (size_t)blockIdx.z * (size_t)NO * V3;

  const int lo = (d < 2) ? (2 - d) : 0;
  const int hi = (d > 45) ? (49 - d) : 4;
  const int kslo = 6 * lo;
  const int T = 6 * (hi - lo + 1);               // 18/24/30 (mult of 6)

  const ushort_t* ap = Afr + ((size_t)(kslo * 4 + quad) * 64 + m15) * 8;
  const ushort_t* bp = Bqb + ((size_t)((d - 2) * 24 + kslo * 4 + quad) * PLANE + n0 + m15) * 8;
  const int astep = 4 * 64 * 8;                  // shorts per trip (4096 B)
  const int bstep = 4 * PLANE * 8;

  float4v acc[4][2];
#pragma unroll
  for (int mt = 0; mt < 4; ++mt)
#pragma unroll
    for (int nt = 0; nt < 2; ++nt) acc[mt][nt] = (float4v){0.f, 0.f, 0.f, 0.f};

  short8v A0[4], B0[2], A1[4], B1[2], A2[4], B2[2];

#define SBAR __builtin_amdgcn_sched_barrier(0)
#define GLOAD(dst, addr, OFF)                                                  \
  asm volatile("global_load_dwordx4 %0, %1, off offset:" #OFF                  \
               : "=v"(dst) : "v"(addr))
#define ISSUE(Ax, Bx)                                                          \
  {                                                                            \
    GLOAD(Bx[0], bp, 0);   GLOAD(Bx[1], bp, 256);                              \
    GLOAD(Ax[0], ap, 0);   GLOAD(Ax[1], ap, 256);                              \
    GLOAD(Ax[2], ap, 512); GLOAD(Ax[3], ap, 768);                              \
    ap += astep; bp += bstep;                                                  \
  }
#define WAITV(N)                                                               \
  asm volatile("s_waitcnt vmcnt(" #N ")" ::: "memory");                        \
  SBAR
#define MFMASET(Ax, Bx)                                                        \
  {                                                                            \
    __builtin_amdgcn_s_setprio(1);                                             \
    _Pragma("unroll") for (int mt = 0; mt < 4; ++mt)                           \
        _Pragma("unroll") for (int nt = 0; nt < 2; ++nt)                       \
            acc[mt][nt] = __builtin_amdgcn_mfma_f32_16x16x32_bf16(             \
                Ax[mt], Bx[nt], acc[mt][nt], 0, 0, 0);                         \
    __builtin_amdgcn_s_setprio(0);                                             \
    SBAR;                                                                      \
  }

  ISSUE(A0, B0);                                 // trip 0
  ISSUE(A1, B1);                                 // trip 1   (12 outstanding)
  for (int k = 0; k < T - 3; k += 3) {
    ISSUE(A2, B2); WAITV(12); MFMASET(A0, B0);   // consume k,   issue k+2
    ISSUE(A0, B0); WAITV(12); MFMASET(A1, B1);   // consume k+1, issue k+3
    ISSUE(A1, B1); WAITV(12); MFMASET(A2, B2);   // consume k+2, issue k+4
  }
  ISSUE(A2, B2);                                 // trip T-1 (18 outstanding)
  WAITV(12); MFMASET(A0, B0);                    // trip T-3
  WAITV(6);  MFMASET(A1, B1);                    // trip T-2
  WAITV(0);  MFMASET(A2, B2);                    // trip T-1
#undef ISSUE
#undef GLOAD
#undef WAITV
#undef MFMASET
#undef SBAR

  // C/D: col(n) = lane&15, row(m) = quad*4 + reg; nontemporal out stores
  const int vb = d * PLANE + n0 + m15;
#pragma unroll
  for (int mt = 0; mt < 4; ++mt) {
#pragma unroll
    for (int r = 0; r < 4; ++r) {
      int m = mt * 16 + quad * 4 + r;
      float bv = bias[m];
      float* op = outb + (size_t)m * V3 + vb;
#pragma unroll
      for (int nt = 0; nt < 2; ++nt)
        __builtin_nontemporal_store(acc[mt][nt][r] + bv, op + nt * 16);
    }
  }
}

extern "C" void kernel_launch(void* const* d_in, const int* in_sizes, int n_in,
                              void* d_out, int out_size, void* d_ws, size_t ws_size,
                              hipStream_t stream) {
  const float* x    = (const float*)d_in[0];   // [2,32,1,48,48,48]
  const float* w    = (const float*)d_in[1];   // [64,32,1,1,1,10]
  const float* bias = (const float*)d_in[2];   // [64]
  float* out = (float*)d_out;                  // [2,64,1,48,48,48]

  ushort_t* Afr = (ushort_t*)d_ws;                         // 122880 B
  ushort_t* Bq  = (ushort_t*)((char*)d_ws + 131072);
  const size_t SB = (size_t)1152 * PLANE * 8 * 2;          // 42.5 MB per batch
  const bool both = (ws_size >= 131072 + 2 * SB);

  if (both) {
    bq_kernel<<<dim3(1536), 256, 0, stream>>>(x, Bq, w, Afr, 0);
    gemm_kernel<<<dim3(864, 1, 2), 256, 0, stream>>>(Bq, Afr, bias, out);
  } else {
    for (int b = 0; b < 2; ++b) {
      bq_kernel<<<dim3(768), 256, 0, stream>>>(x + (size_t)b * 32 * V3, Bq, w, Afr, 0);
      gemm_kernel<<<dim3(864, 1, 1), 256, 0, stream>>>(Bq, Afr, bias,
                                                       out + (size_t)b * NO * V3);
    }
  }
}